// Round 8
// baseline (817.538 us; speedup 1.0000x reference)
//
#include <hip/hip_runtime.h>
#include <hip/hip_cooperative_groups.h>

namespace cg = cooperative_groups;

#define NN 100000
#define DD 128
#define EE 640000
#define GRID 512
#define NPB 198              // nodes per block in coop scan; GRID*NPB = 101376
#define NPAD 101376          // = 512*198 = 1024*99 (works for both scan paths)
#define TILES 1563           // ceil(NN/64)
#define SPAD 16              // stats: one word per 64B line

typedef __bf16 bf16x8 __attribute__((ext_vector_type(8)));
typedef float floatx4 __attribute__((ext_vector_type(4)));

union FragU { int4 i; bf16x8 b; unsigned short us[8]; };

__device__ __forceinline__ unsigned short f2bf(float f) {
    unsigned int u = __float_as_uint(f);
    u += 0x7FFF + ((u >> 16) & 1);   // RNE
    return (unsigned short)(u >> 16);
}
__device__ __forceinline__ float bf2f(unsigned short u) {
    return __uint_as_float(((unsigned int)u) << 16);
}
__device__ __forceinline__ void addbf8(float* acc, int4 raw) {
    unsigned int u0 = (unsigned int)raw.x, u1 = (unsigned int)raw.y;
    unsigned int u2 = (unsigned int)raw.z, u3 = (unsigned int)raw.w;
    acc[0] += __uint_as_float(u0 << 16);
    acc[1] += __uint_as_float(u0 & 0xffff0000u);
    acc[2] += __uint_as_float(u1 << 16);
    acc[3] += __uint_as_float(u1 & 0xffff0000u);
    acc[4] += __uint_as_float(u2 << 16);
    acc[5] += __uint_as_float(u2 & 0xffff0000u);
    acc[6] += __uint_as_float(u3 << 16);
    acc[7] += __uint_as_float(u3 & 0xffff0000u);
}

struct Params {
    const float4* x4; const int* ei; const float* eps;
    const float4* W1f; const float* b1; const float* g1; const float* be1;
    const float4* W2f; const float* b2; const float* g2; const float* be2;
    float* out;
    int* deg; int* cursor; int* ssrc;
    unsigned short* hbuf; unsigned short* wb1; unsigned short* wb2;
    int* blockSum; int* blockBase; float* stats;
    unsigned short* xb;
};

// ---------------------------------------------------------------------------
// shared device phases (used by both coop kernel and fallback kernels)
// ---------------------------------------------------------------------------
template <int MODE>
__device__ __forceinline__ void gemm_tile(
    unsigned short* hio, const float* bias_sc_sh_unused, int tile,
    const unsigned short (&Bs)[128][132], const float* sc, const float* sh,
    const float* bc, float* psum, float* psq, int w, int m, int q) {
    const int rA = tile * 64 + w * 16 + m;
    const int rAc = (rA < NN) ? rA : (NN - 1);
    FragU a[4];
#pragma unroll
    for (int kc = 0; kc < 4; ++kc)
        a[kc].i = *(const int4*)(hio + rAc * 128 + kc * 32 + q * 8);

    if (MODE == 1) {
#pragma unroll
        for (int kc = 0; kc < 4; ++kc) {
            int k0 = kc * 32 + q * 8;
            float4 sA = *(const float4*)&sc[k0], sB = *(const float4*)&sc[k0 + 4];
            float4 hA = *(const float4*)&sh[k0], hB = *(const float4*)&sh[k0 + 4];
            FragU u = a[kc];
            u.us[0] = f2bf(fmaxf(bf2f(u.us[0]) * sA.x + hA.x, 0.f));
            u.us[1] = f2bf(fmaxf(bf2f(u.us[1]) * sA.y + hA.y, 0.f));
            u.us[2] = f2bf(fmaxf(bf2f(u.us[2]) * sA.z + hA.z, 0.f));
            u.us[3] = f2bf(fmaxf(bf2f(u.us[3]) * sA.w + hA.w, 0.f));
            u.us[4] = f2bf(fmaxf(bf2f(u.us[4]) * sB.x + hB.x, 0.f));
            u.us[5] = f2bf(fmaxf(bf2f(u.us[5]) * sB.y + hB.y, 0.f));
            u.us[6] = f2bf(fmaxf(bf2f(u.us[6]) * sB.z + hB.z, 0.f));
            u.us[7] = f2bf(fmaxf(bf2f(u.us[7]) * sB.w + hB.w, 0.f));
            a[kc] = u;
        }
    }

    floatx4 acc[8];
#pragma unroll
    for (int ct = 0; ct < 8; ++ct) acc[ct] = (floatx4)0.0f;
#pragma unroll
    for (int kc = 0; kc < 4; ++kc) {
        int k0 = kc * 32 + q * 8;
#pragma unroll
        for (int ct = 0; ct < 8; ++ct) {
            bf16x8 b = *(const bf16x8*)&Bs[ct * 16 + m][k0];
            acc[ct] = __builtin_amdgcn_mfma_f32_16x16x32_bf16(a[kc].b, b, acc[ct], 0, 0, 0);
        }
    }
#pragma unroll
    for (int ct = 0; ct < 8; ++ct) {
        int col = ct * 16 + m;
#pragma unroll
        for (int i = 0; i < 4; ++i) {
            int rg = tile * 64 + w * 16 + q * 4 + i;
            if (rg < NN) {
                float yv = acc[ct][i] + bc[ct];
                hio[rg * 128 + col] = f2bf(yv);
                psum[ct] += yv;
                psq[ct] += yv * yv;
            }
        }
    }
}

template <int MODE>
__device__ __forceinline__ void gemm_phase(
    unsigned short* hio, const unsigned short* Wb, const float* bias,
    const float* stats_in, const float* g, const float* be, float* stats_out,
    unsigned short (&Bs)[128][132], float* sc, float* sh,
    float* s_sum, float* s_sq, int tile0, int tileStride) {
    const int tid = threadIdx.x;
    if (tid < 128) {
        s_sum[tid] = 0.f; s_sq[tid] = 0.f;
        if (MODE == 1) {
            const float inv = 1.0f / (float)NN;
            float mean = stats_in[tid * SPAD] * inv;
            float var = stats_in[(128 + tid) * SPAD] * inv - mean * mean;
            float s = g[tid] * rsqrtf(var + 1e-5f);
            sc[tid] = s;
            sh[tid] = be[tid] - mean * s;
        }
    }
#pragma unroll
    for (int it = 0; it < 8; ++it) {
        int idx = it * 256 + tid;
        int row = idx >> 4, c8 = (idx & 15) * 8;
        *(int4*)&Bs[row][c8] = *(const int4*)(Wb + row * 128 + c8);
    }
    __syncthreads();

    const int w = tid >> 6, l = tid & 63, m = l & 15, q = l >> 4;
    float bc[8], psum[8], psq[8];
#pragma unroll
    for (int ct = 0; ct < 8; ++ct) {
        bc[ct] = bias[ct * 16 + m];
        psum[ct] = 0.f; psq[ct] = 0.f;
    }

    for (int tile = tile0; tile < TILES; tile += tileStride)
        gemm_tile<MODE>(hio, nullptr, tile, Bs, sc, sh, bc, psum, psq, w, m, q);

    // stats: butterfly over q (lanes ^16, ^32), then LDS, then global atomic
#pragma unroll
    for (int ct = 0; ct < 8; ++ct) {
        float v = psum[ct];
        v += __shfl_xor(v, 16); v += __shfl_xor(v, 32);
        float z = psq[ct];
        z += __shfl_xor(z, 16); z += __shfl_xor(z, 32);
        if (q == 0) {
            atomicAdd(&s_sum[ct * 16 + m], v);
            atomicAdd(&s_sq[ct * 16 + m], z);
        }
    }
    __syncthreads();
    if (tid < 128) {
        atomicAdd(&stats_out[tid * SPAD], s_sum[tid]);
        atomicAdd(&stats_out[(128 + tid) * SPAD], s_sq[tid]);
    }
}

__device__ __forceinline__ void aggregate_chunk(
    const unsigned short* xb, const int* ssrc, const int* cursor,
    const int* deg, float ef, unsigned short* hout, int t) {
    int node = t >> 4, lane = t & 15;
    int d = deg[node];
    int start = cursor[node] - d;   // cursor==end after esort
    float acc[8] = {0, 0, 0, 0, 0, 0, 0, 0};
    {
        int4 raw = *(const int4*)(xb + node * 128 + lane * 8);
        addbf8(acc, raw);
#pragma unroll
        for (int i = 0; i < 8; ++i) acc[i] *= ef;
    }
    int j = 0;
    for (; j + 4 <= d; j += 4) {
        int s0 = ssrc[start + j + 0];
        int s1 = ssrc[start + j + 1];
        int s2 = ssrc[start + j + 2];
        int s3 = ssrc[start + j + 3];
        int4 r0 = *(const int4*)(xb + s0 * 128 + lane * 8);
        int4 r1 = *(const int4*)(xb + s1 * 128 + lane * 8);
        int4 r2 = *(const int4*)(xb + s2 * 128 + lane * 8);
        int4 r3 = *(const int4*)(xb + s3 * 128 + lane * 8);
        addbf8(acc, r0); addbf8(acc, r1); addbf8(acc, r2); addbf8(acc, r3);
    }
    for (; j < d; ++j) {
        int s = ssrc[start + j];
        int4 r = *(const int4*)(xb + s * 128 + lane * 8);
        addbf8(acc, r);
    }
    FragU o;
#pragma unroll
    for (int i = 0; i < 8; ++i) o.us[i] = f2bf(acc[i]);
    *(int4*)(hout + node * 128 + lane * 8) = o.i;
}

__device__ __forceinline__ void bn_final_chunk(
    const unsigned short* y, float* out, const float* sc, const float* sh,
    int i) {
    int c8 = (i & 15) * 8;
    int4 raw = ((const int4*)y)[i];
    float v[8] = {0, 0, 0, 0, 0, 0, 0, 0};
    addbf8(v, raw);
    float4 sA = *(const float4*)&sc[c8], sB = *(const float4*)&sc[c8 + 4];
    float4 hA = *(const float4*)&sh[c8], hB = *(const float4*)&sh[c8 + 4];
    float4 o0, o1;
    o0.x = fmaxf(v[0] * sA.x + hA.x, 0.f);
    o0.y = fmaxf(v[1] * sA.y + hA.y, 0.f);
    o0.z = fmaxf(v[2] * sA.z + hA.z, 0.f);
    o0.w = fmaxf(v[3] * sA.w + hA.w, 0.f);
    o1.x = fmaxf(v[4] * sB.x + hB.x, 0.f);
    o1.y = fmaxf(v[5] * sB.y + hB.y, 0.f);
    o1.z = fmaxf(v[6] * sB.z + hB.z, 0.f);
    o1.w = fmaxf(v[7] * sB.w + hB.w, 0.f);
    ((float4*)out)[i * 2] = o0;
    ((float4*)out)[i * 2 + 1] = o1;
}

// ---------------------------------------------------------------------------
// cooperative mega-kernel
// ---------------------------------------------------------------------------
__global__ __launch_bounds__(256, 2) void fused_k(Params p) {
    __shared__ __align__(16) unsigned short Bs[128][132];
    __shared__ __align__(16) float sc[128], sh[128], s_sum[128], s_sq[128];
    __shared__ int sArr[256];

    cg::grid_group grid = cg::this_grid();
    const int tid = threadIdx.x;
    const int bid = blockIdx.x;
    const int gtid = bid * 256 + tid;
    const int gsz = GRID * 256;

    // ---- P0: zero deg + stats ----
    for (int i = gtid; i < NPAD; i += gsz) p.deg[i] = 0;
    for (int i = gtid; i < 2 * 512 * SPAD; i += gsz) p.stats[i] = 0.f;
    grid.sync();

    // ---- P1: histogram + x->bf16 + W->bf16 ----
    for (int e = gtid; e < EE; e += gsz) atomicAdd(&p.deg[p.ei[EE + e]], 1);
    for (int i = gtid; i < NN * 32; i += gsz) {
        float4 v = p.x4[i];
        ushort4 u;
        u.x = f2bf(v.x); u.y = f2bf(v.y); u.z = f2bf(v.z); u.w = f2bf(v.w);
        ((ushort4*)p.xb)[i] = u;
    }
    for (int i = gtid; i < 8192; i += gsz) {
        float4 v = (i < 4096) ? p.W1f[i] : p.W2f[i - 4096];
        ushort4 u;
        u.x = f2bf(v.x); u.y = f2bf(v.y); u.z = f2bf(v.z); u.w = f2bf(v.w);
        ushort4* dst = (i < 4096) ? (ushort4*)p.wb1 : (ushort4*)p.wb2;
        dst[i & 4095] = u;
    }
    grid.sync();

    // ---- P2a: block-local scan of deg (NPB elems) ----
    {
        int g = bid * NPB + tid;
        int v = (tid < NPB) ? p.deg[g] : 0;
        sArr[tid] = v;
        __syncthreads();
        for (int off = 1; off < 256; off <<= 1) {
            int u = (tid >= off) ? sArr[tid - off] : 0;
            __syncthreads();
            sArr[tid] += u;
            __syncthreads();
        }
        if (tid < NPB) p.cursor[g] = sArr[tid] - v;
        if (tid == 255) p.blockSum[bid] = sArr[255];
    }
    grid.sync();

    // ---- P2b: block 0 scans blockSum[GRID=512] (2/thread) ----
    if (bid == 0) {
        int e0 = p.blockSum[2 * tid], e1 = p.blockSum[2 * tid + 1];
        int s2 = e0 + e1;
        sArr[tid] = s2;
        __syncthreads();
        for (int off = 1; off < 256; off <<= 1) {
            int u = (tid >= off) ? sArr[tid - off] : 0;
            __syncthreads();
            sArr[tid] += u;
            __syncthreads();
        }
        int excl = sArr[tid] - s2;
        p.blockBase[2 * tid] = excl;
        p.blockBase[2 * tid + 1] = excl + e0;
    }
    grid.sync();

    // ---- P2c: apply block base ----
    if (tid < NPB) p.cursor[bid * NPB + tid] += p.blockBase[bid];
    grid.sync();

    // ---- P3: esort ----
    for (int e = gtid; e < EE; e += gsz) {
        int pos = atomicAdd(&p.cursor[p.ei[EE + e]], 1);
        p.ssrc[pos] = p.ei[e];
    }
    grid.sync();

    // ---- P4: aggregate ----
    {
        const float ef = 1.0f + p.eps[0];
        for (int t = gtid; t < NN * 16; t += gsz)
            aggregate_chunk(p.xb, p.ssrc, p.cursor, p.deg, ef, p.hbuf, t);
    }
    grid.sync();

    // ---- P5: gemm1 ----
    gemm_phase<0>(p.hbuf, p.wb1, p.b1, nullptr, nullptr, nullptr, p.stats,
                  Bs, sc, sh, s_sum, s_sq, bid, GRID);
    grid.sync();

    // ---- P6: gemm2 (BN1+ReLU fused) ----
    gemm_phase<1>(p.hbuf, p.wb2, p.b2, p.stats, p.g1, p.be1,
                  p.stats + 512 * SPAD, Bs, sc, sh, s_sum, s_sq, bid, GRID);
    grid.sync();

    // ---- P7: final BN + ReLU -> fp32 out ----
    {
        const float* st2 = p.stats + 512 * SPAD;
        if (tid < 128) {
            const float inv = 1.0f / (float)NN;
            float mean = st2[tid * SPAD] * inv;
            float var = st2[(128 + tid) * SPAD] * inv - mean * mean;
            float s = p.g2[tid] * rsqrtf(var + 1e-5f);
            sc[tid] = s;
            sh[tid] = p.be2[tid] - mean * s;
        }
        __syncthreads();
        for (int i = gtid; i < NN * 16; i += gsz)
            bn_final_chunk(p.hbuf, p.out, sc, sh, i);
    }
}

// ---------------------------------------------------------------------------
// fallback multi-kernel pipeline (R6 structure, shared layout)
// ---------------------------------------------------------------------------
#define HBLK 2500
#define XBLK 3200
__global__ __launch_bounds__(256) void pre_k(Params p) {
    int bid = blockIdx.x;
    if (bid < HBLK) {
        int e = bid * 256 + threadIdx.x;
        atomicAdd(&p.deg[p.ei[EE + e]], 1);
    } else if (bid < HBLK + XBLK) {
        for (int i = (bid - HBLK) * 256 + threadIdx.x; i < NN * 32;
             i += XBLK * 256) {
            float4 v = p.x4[i];
            ushort4 u;
            u.x = f2bf(v.x); u.y = f2bf(v.y); u.z = f2bf(v.z); u.w = f2bf(v.w);
            ((ushort4*)p.xb)[i] = u;
        }
    } else {
        int wb = bid - HBLK - XBLK;
        const float4* src = (wb < 16) ? p.W1f : p.W2f;
        ushort4* dst = (wb < 16) ? (ushort4*)p.wb1 : (ushort4*)p.wb2;
        int i = (wb & 15) * 256 + threadIdx.x;
        float4 v = src[i];
        ushort4 u;
        u.x = f2bf(v.x); u.y = f2bf(v.y); u.z = f2bf(v.z); u.w = f2bf(v.w);
        dst[i] = u;
    }
}

__global__ __launch_bounds__(1024) void scan_fb_k(Params p) {
    __shared__ int part[1024];
    int t = threadIdx.x;
#pragma unroll
    for (int j = 0; j < 16; ++j) p.stats[j * 1024 + t] = 0.f;
    int base = t * 99;                 // 1024*99 == NPAD
    int s = 0;
    for (int j = 0; j < 99; ++j) s += p.deg[base + j];
    part[t] = s;
    __syncthreads();
    for (int off = 1; off < 1024; off <<= 1) {
        int u = (t >= off) ? part[t - off] : 0;
        __syncthreads();
        part[t] += u;
        __syncthreads();
    }
    int run = part[t] - s;
    for (int j = 0; j < 99; ++j) {
        int idx = base + j;
        p.cursor[idx] = run;
        run += p.deg[idx];
    }
}

__global__ __launch_bounds__(256) void esort_fb_k(Params p) {
    int e = blockIdx.x * 256 + threadIdx.x;
    if (e >= EE) return;
    int pos = atomicAdd(&p.cursor[p.ei[EE + e]], 1);
    p.ssrc[pos] = p.ei[e];
}

__global__ __launch_bounds__(256) void aggregate_fb_k(Params p) {
    int t = blockIdx.x * 256 + threadIdx.x;
    if (t >= NN * 16) return;
    aggregate_chunk(p.xb, p.ssrc, p.cursor, p.deg, 1.0f + p.eps[0], p.hbuf, t);
}

template <int MODE>
__global__ __launch_bounds__(256) void gemm_fb_k(Params p) {
    __shared__ __align__(16) unsigned short Bs[128][132];
    __shared__ __align__(16) float sc[128], sh[128], s_sum[128], s_sq[128];
    const unsigned short* Wb = (MODE == 0) ? p.wb1 : p.wb2;
    const float* bias = (MODE == 0) ? p.b1 : p.b2;
    float* so = (MODE == 0) ? p.stats : (p.stats + 512 * SPAD);
    gemm_phase<MODE>(p.hbuf, Wb, bias, p.stats, p.g1, p.be1, so,
                     Bs, sc, sh, s_sum, s_sq, blockIdx.x, TILES);
}

__global__ __launch_bounds__(256) void bn_final_fb_k(Params p) {
    __shared__ __align__(16) float sc[128], sh[128];
    const float* st2 = p.stats + 512 * SPAD;
    int t = threadIdx.x;
    if (t < 128) {
        const float inv = 1.0f / (float)NN;
        float mean = st2[t * SPAD] * inv;
        float var = st2[(128 + t) * SPAD] * inv - mean * mean;
        float s = p.g2[t] * rsqrtf(var + 1e-5f);
        sc[t] = s;
        sh[t] = p.be2[t] - mean * s;
    }
    __syncthreads();
    int i = blockIdx.x * 256 + t;
    if (i < NN * 16) bn_final_chunk(p.hbuf, p.out, sc, sh, i);
}

// ---------------------------------------------------------------------------
extern "C" void kernel_launch(void* const* d_in, const int* in_sizes, int n_in,
                              void* d_out, int out_size, void* d_ws, size_t ws_size,
                              hipStream_t stream) {
    Params p;
    p.x4  = (const float4*)d_in[0];
    p.ei  = (const int*)d_in[1];     // int64 in ref -> int32 from harness
    p.eps = (const float*)d_in[2];
    p.W1f = (const float4*)d_in[3];
    p.b1  = (const float*)d_in[4];
    p.g1  = (const float*)d_in[5];
    p.be1 = (const float*)d_in[6];
    p.W2f = (const float4*)d_in[7];
    p.b2  = (const float*)d_in[8];
    p.g2  = (const float*)d_in[9];
    p.be2 = (const float*)d_in[10];
    p.out = (float*)d_out;

    int* w      = (int*)d_ws;
    p.deg       = w; w += NPAD;
    p.cursor    = w; w += NPAD;
    p.ssrc      = w; w += EE;
    p.blockSum  = w; w += GRID;
    p.blockBase = w; w += GRID;
    p.hbuf = (unsigned short*)w;
    p.wb1  = p.hbuf + (size_t)NN * DD;
    p.wb2  = p.wb1 + 16384;
    p.stats = (float*)(p.wb2 + 16384);        // 2*512*SPAD floats
    p.xb = (unsigned short*)d_out;            // bf16 x, dead before final BN

    void* args[] = {&p};
    hipError_t err = hipLaunchCooperativeKernel((void*)fused_k, dim3(GRID),
                                                dim3(256), args, 0, stream);
    if (err != hipSuccess) {
        (void)hipGetLastError();   // clear sticky error, run fallback
        hipMemsetAsync(p.deg, 0, NPAD * sizeof(int), stream);
        pre_k<<<HBLK + XBLK + 32, 256, 0, stream>>>(p);
        scan_fb_k<<<1, 1024, 0, stream>>>(p);
        esort_fb_k<<<(EE + 255) / 256, 256, 0, stream>>>(p);
        aggregate_fb_k<<<NN * 16 / 256, 256, 0, stream>>>(p);
        gemm_fb_k<0><<<TILES, 256, 0, stream>>>(p);
        gemm_fb_k<1><<<TILES, 256, 0, stream>>>(p);
        bn_final_fb_k<<<NN * 16 / 256, 256, 0, stream>>>(p);
    }
}